// Round 2
// baseline (391.850 us; speedup 1.0000x reference)
//
#include <hip/hip_runtime.h>

#define B_ 8
#define C_ 256
#define N_ 4096
#define NH_ 8
#define HD_ 32

#define ALPHA_ 0.36787944117144233f   // elu(-1)+1 = e^-1
#define BETAS_ (2.0f - ALPHA_)        // k/q spike value 2.0 = ALPHA_ + BETAS_
#define SCALE_ 0.17677669529663687f   // 32^-0.5

// ---------------------------------------------------------------------------
// K1: fused QKV conv1x1 + LIF.  out_c[o,n] = LIF(sum_i W_c[o,i]*X[b,i,n], mem_c)
// Tile 128(o) x 128(n) x 32(k), 256 threads, 8x8 micro-tile per conv.
// X staged ONCE for all three convs -> 192 FMA per Xs fragment read.
// Xs uses 8-float chunks at stride-12 floats (48B) -> bank period 8 chunks,
// only 2-way aliasing on ds_read_b128 (free).  Row pad 196 (+4 banks/row).
// ---------------------------------------------------------------------------
__global__ __launch_bounds__(256, 2) void gemm_qkv(
    const float* __restrict__ x,
    const float* __restrict__ Wq, const float* __restrict__ Wk, const float* __restrict__ Wv,
    const float* __restrict__ qm, const float* __restrict__ km, const float* __restrict__ vm,
    float* __restrict__ oq, float* __restrict__ ok, float* __restrict__ ov)
{
    int b = blockIdx.z;
    const float* Xb = x + (size_t)b * C_ * N_;
    int oT = blockIdx.y * 128;
    int nT = blockIdx.x * 128;

    __shared__ float Xs[32][196];                 // chunked layout
    __shared__ float Wqs[32][132], Wks[32][132], Wvs[32][132];

    int t  = threadIdx.x;
    int tx = t & 15;
    int ty = t >> 4;

    float accq[8][8], acck[8][8], accv[8][8];
    #pragma unroll
    for (int i = 0; i < 8; ++i)
        #pragma unroll
        for (int j = 0; j < 8; ++j) { accq[i][j] = 0.f; acck[i][j] = 0.f; accv[i][j] = 0.f; }

    for (int k0 = 0; k0 < C_; k0 += 32) {
        // ---- stage 3 W tiles (transposed: Ws[k][o]) ----
        {
            int r = t >> 1;             // 0..127
            int c = (t & 1) * 16;       // 0 or 16
            size_t wb = (size_t)(oT + r) * C_ + k0 + c;
            const float4* sq = reinterpret_cast<const float4*>(&Wq[wb]);
            const float4* sk = reinterpret_cast<const float4*>(&Wk[wb]);
            const float4* sv = reinterpret_cast<const float4*>(&Wv[wb]);
            #pragma unroll
            for (int q = 0; q < 4; ++q) {
                float4 w4 = sq[q];
                Wqs[c + q*4 + 0][r] = w4.x; Wqs[c + q*4 + 1][r] = w4.y;
                Wqs[c + q*4 + 2][r] = w4.z; Wqs[c + q*4 + 3][r] = w4.w;
            }
            #pragma unroll
            for (int q = 0; q < 4; ++q) {
                float4 w4 = sk[q];
                Wks[c + q*4 + 0][r] = w4.x; Wks[c + q*4 + 1][r] = w4.y;
                Wks[c + q*4 + 2][r] = w4.z; Wks[c + q*4 + 3][r] = w4.w;
            }
            #pragma unroll
            for (int q = 0; q < 4; ++q) {
                float4 w4 = sv[q];
                Wvs[c + q*4 + 0][r] = w4.x; Wvs[c + q*4 + 1][r] = w4.y;
                Wvs[c + q*4 + 2][r] = w4.z; Wvs[c + q*4 + 3][r] = w4.w;
            }
        }
        // ---- stage X tile (chunked) ----
        {
            int kk = t >> 3;            // 0..31
            int cn = (t & 7) * 16;      // 0..112
            const float4* sx = reinterpret_cast<const float4*>(&Xb[(size_t)(k0 + kk) * N_ + nT + cn]);
            #pragma unroll
            for (int q = 0; q < 4; ++q) {
                float4 v = sx[q];
                int nl = cn + q * 4;
                int ch = nl >> 3, wi = nl & 7;
                *reinterpret_cast<float4*>(&Xs[kk][ch * 12 + wi]) = v;
            }
        }
        __syncthreads();

        #pragma unroll
        for (int kk = 0; kk < 32; ++kk) {
            float bb[8];
            *reinterpret_cast<float4*>(&bb[0]) = *reinterpret_cast<const float4*>(&Xs[kk][tx*12]);
            *reinterpret_cast<float4*>(&bb[4]) = *reinterpret_cast<const float4*>(&Xs[kk][tx*12 + 4]);
            {
                float a[8];
                *reinterpret_cast<float4*>(&a[0]) = *reinterpret_cast<const float4*>(&Wqs[kk][ty*8]);
                *reinterpret_cast<float4*>(&a[4]) = *reinterpret_cast<const float4*>(&Wqs[kk][ty*8+4]);
                #pragma unroll
                for (int i = 0; i < 8; ++i)
                    #pragma unroll
                    for (int j = 0; j < 8; ++j) accq[i][j] += a[i] * bb[j];
            }
            {
                float a[8];
                *reinterpret_cast<float4*>(&a[0]) = *reinterpret_cast<const float4*>(&Wks[kk][ty*8]);
                *reinterpret_cast<float4*>(&a[4]) = *reinterpret_cast<const float4*>(&Wks[kk][ty*8+4]);
                #pragma unroll
                for (int i = 0; i < 8; ++i)
                    #pragma unroll
                    for (int j = 0; j < 8; ++j) acck[i][j] += a[i] * bb[j];
            }
            {
                float a[8];
                *reinterpret_cast<float4*>(&a[0]) = *reinterpret_cast<const float4*>(&Wvs[kk][ty*8]);
                *reinterpret_cast<float4*>(&a[4]) = *reinterpret_cast<const float4*>(&Wvs[kk][ty*8+4]);
                #pragma unroll
                for (int i = 0; i < 8; ++i)
                    #pragma unroll
                    for (int j = 0; j < 8; ++j) accv[i][j] += a[i] * bb[j];
            }
        }
        __syncthreads();
    }

    // ---- LIF epilogue, all three convs ----
    #pragma unroll
    for (int i = 0; i < 8; ++i) {
        int o = oT + ty*8 + i;
        size_t base = ((size_t)b * C_ + o) * N_ + nT + tx*8;
        #pragma unroll
        for (int half = 0; half < 2; ++half) {
            float4 m4, r4;
            m4 = *reinterpret_cast<const float4*>(&qm[base + half*4]);
            r4.x = 0.5f*m4.x + accq[i][half*4+0] - (m4.x > 1.0f ? 1.0f : 0.0f);
            r4.y = 0.5f*m4.y + accq[i][half*4+1] - (m4.y > 1.0f ? 1.0f : 0.0f);
            r4.z = 0.5f*m4.z + accq[i][half*4+2] - (m4.z > 1.0f ? 1.0f : 0.0f);
            r4.w = 0.5f*m4.w + accq[i][half*4+3] - (m4.w > 1.0f ? 1.0f : 0.0f);
            *reinterpret_cast<float4*>(&oq[base + half*4]) = r4;

            m4 = *reinterpret_cast<const float4*>(&km[base + half*4]);
            r4.x = 0.5f*m4.x + acck[i][half*4+0] - (m4.x > 1.0f ? 1.0f : 0.0f);
            r4.y = 0.5f*m4.y + acck[i][half*4+1] - (m4.y > 1.0f ? 1.0f : 0.0f);
            r4.z = 0.5f*m4.z + acck[i][half*4+2] - (m4.z > 1.0f ? 1.0f : 0.0f);
            r4.w = 0.5f*m4.w + acck[i][half*4+3] - (m4.w > 1.0f ? 1.0f : 0.0f);
            *reinterpret_cast<float4*>(&ok[base + half*4]) = r4;

            m4 = *reinterpret_cast<const float4*>(&vm[base + half*4]);
            r4.x = 0.5f*m4.x + accv[i][half*4+0] - (m4.x > 1.0f ? 1.0f : 0.0f);
            r4.y = 0.5f*m4.y + accv[i][half*4+1] - (m4.y > 1.0f ? 1.0f : 0.0f);
            r4.z = 0.5f*m4.z + accv[i][half*4+2] - (m4.z > 1.0f ? 1.0f : 0.0f);
            r4.w = 0.5f*m4.w + accv[i][half*4+3] - (m4.w > 1.0f ? 1.0f : 0.0f);
            *reinterpret_cast<float4*>(&ov[base + half*4]) = r4;
        }
    }
}

// ---------------------------------------------------------------------------
// K4: Wo conv (plain GEMM, same tile scheme, chunk-swizzled Xs).
// ---------------------------------------------------------------------------
__global__ __launch_bounds__(256) void gemm_wo(
    const float* __restrict__ Xall, const float* __restrict__ W,
    float* __restrict__ out)
{
    int b = blockIdx.z;
    const float* Xb = Xall + (size_t)b * C_ * N_;
    int oT = blockIdx.y * 128;
    int nT = blockIdx.x * 128;

    __shared__ float Ws[32][132];
    __shared__ float Xs[32][196];

    int t  = threadIdx.x;
    int tx = t & 15;
    int ty = t >> 4;

    float acc[8][8];
    #pragma unroll
    for (int i = 0; i < 8; ++i)
        #pragma unroll
        for (int j = 0; j < 8; ++j) acc[i][j] = 0.0f;

    for (int k0 = 0; k0 < C_; k0 += 32) {
        {
            int r = t >> 1;
            int c = (t & 1) * 16;
            const float4* src = reinterpret_cast<const float4*>(&W[(size_t)(oT + r) * C_ + k0 + c]);
            #pragma unroll
            for (int q = 0; q < 4; ++q) {
                float4 w4 = src[q];
                Ws[c + q*4 + 0][r] = w4.x; Ws[c + q*4 + 1][r] = w4.y;
                Ws[c + q*4 + 2][r] = w4.z; Ws[c + q*4 + 3][r] = w4.w;
            }
        }
        {
            int kk = t >> 3;
            int cn = (t & 7) * 16;
            const float4* src = reinterpret_cast<const float4*>(&Xb[(size_t)(k0 + kk) * N_ + nT + cn]);
            #pragma unroll
            for (int q = 0; q < 4; ++q) {
                float4 v = src[q];
                int nl = cn + q * 4;
                int ch = nl >> 3, wi = nl & 7;
                *reinterpret_cast<float4*>(&Xs[kk][ch * 12 + wi]) = v;
            }
        }
        __syncthreads();
        #pragma unroll
        for (int kk = 0; kk < 32; ++kk) {
            float a[8], bb[8];
            *reinterpret_cast<float4*>(&a[0])  = *reinterpret_cast<const float4*>(&Ws[kk][ty*8]);
            *reinterpret_cast<float4*>(&a[4])  = *reinterpret_cast<const float4*>(&Ws[kk][ty*8+4]);
            *reinterpret_cast<float4*>(&bb[0]) = *reinterpret_cast<const float4*>(&Xs[kk][tx*12]);
            *reinterpret_cast<float4*>(&bb[4]) = *reinterpret_cast<const float4*>(&Xs[kk][tx*12 + 4]);
            #pragma unroll
            for (int i = 0; i < 8; ++i)
                #pragma unroll
                for (int j = 0; j < 8; ++j)
                    acc[i][j] += a[i] * bb[j];
        }
        __syncthreads();
    }

    #pragma unroll
    for (int i = 0; i < 8; ++i) {
        int o = oT + ty*8 + i;
        size_t base = ((size_t)b * C_ + o) * N_ + nT + tx*8;
        *reinterpret_cast<float4*>(&out[base])     = make_float4(acc[i][0], acc[i][1], acc[i][2], acc[i][3]);
        *reinterpret_cast<float4*>(&out[base + 4]) = make_float4(acc[i][4], acc[i][5], acc[i][6], acc[i][7]);
    }
}

// ---------------------------------------------------------------------------
// K2: kv[d,e] = sum_n k[n,d]*v[n,e],  ksum[d] = sum_n k[n,d]  per (b,h)
// Exact via 64-bit ballot masks + popcount.
// ---------------------------------------------------------------------------
__global__ __launch_bounds__(256) void kv_kernel(
    const float* __restrict__ Km, const float* __restrict__ Vm,
    float* __restrict__ kvp, float* __restrict__ ksump)
{
    int bh = blockIdx.x;            // 0..63
    int b = bh >> 3, h = bh & 7;
    const float* Kp = Km + ((size_t)(b * C_ + h * HD_)) * N_;
    const float* Vp = Vm + ((size_t)(b * C_ + h * HD_)) * N_;

    __shared__ unsigned long long mk[32][65];
    __shared__ unsigned long long mv[32][65];
    __shared__ float cntk[32], cntv[32];

    int t = threadIdx.x;
    int wave = t >> 6, lane = t & 63;

    for (int r = wave; r < 32; r += 4) {
        const float* kr = Kp + (size_t)r * N_;
        const float* vr = Vp + (size_t)r * N_;
        for (int w4 = 0; w4 < 16; ++w4) {
            float4 kf = *reinterpret_cast<const float4*>(&kr[w4 * 256 + lane * 4]);
            float4 vf = *reinterpret_cast<const float4*>(&vr[w4 * 256 + lane * 4]);
            unsigned long long k0 = __ballot(kf.x > 1.0f);
            unsigned long long k1 = __ballot(kf.y > 1.0f);
            unsigned long long k2 = __ballot(kf.z > 1.0f);
            unsigned long long k3 = __ballot(kf.w > 1.0f);
            unsigned long long v0 = __ballot(vf.x > 1.0f);
            unsigned long long v1 = __ballot(vf.y > 1.0f);
            unsigned long long v2 = __ballot(vf.z > 1.0f);
            unsigned long long v3 = __ballot(vf.w > 1.0f);
            if (lane == 0) {
                mk[r][w4*4+0] = k0; mk[r][w4*4+1] = k1; mk[r][w4*4+2] = k2; mk[r][w4*4+3] = k3;
                mv[r][w4*4+0] = v0; mv[r][w4*4+1] = v1; mv[r][w4*4+2] = v2; mv[r][w4*4+3] = v3;
            }
        }
    }
    __syncthreads();

    if (t < 32) {
        int c = 0;
        for (int w = 0; w < 64; ++w) c += __popcll(mk[t][w]);
        cntk[t] = (float)c;
    } else if (t < 64) {
        int d = t - 32, c = 0;
        for (int w = 0; w < 64; ++w) c += __popcll(mv[d][w]);
        cntv[d] = (float)c;
    }
    __syncthreads();

    int d  = t >> 3;
    int e0 = (t & 7) * 4;
    #pragma unroll
    for (int j = 0; j < 4; ++j) {
        int e = e0 + j;
        int P = 0;
        for (int w = 0; w < 64; ++w) P += __popcll(mk[d][w] & mv[e][w]);
        float skv = 2.0f * (float)P - cntk[d];
        float sv  = 2.0f * cntv[e] - 4096.0f;
        kvp[(size_t)bh * 1024 + d * 32 + e] = ALPHA_ * sv + BETAS_ * skv;
    }
    if ((t & 7) == 0)
        ksump[bh * 32 + d] = ALPHA_ * 4096.0f + BETAS_ * cntk[d];
}

// ---------------------------------------------------------------------------
// K3: att[b, h*32+e, n] = SCALE * (sum_d q[n,d]*kv[d,e]) / (sum_d q[n,d]*ksum[d] + 1e-6)
// ---------------------------------------------------------------------------
__global__ __launch_bounds__(256) void att_kernel(
    const float* __restrict__ Qm, const float* __restrict__ kvp,
    const float* __restrict__ ksump, float* __restrict__ att)
{
    int bh = blockIdx.y; int b = bh >> 3, h = bh & 7;
    int n0 = blockIdx.x * 256;
    const float* Qp = Qm + ((size_t)(b * C_ + h * HD_)) * N_;

    __shared__ float qs[32][260];

    int t = threadIdx.x;
    {
        int r  = t >> 3;
        int c0 = (t & 7) * 32;
        #pragma unroll
        for (int q4 = 0; q4 < 8; ++q4) {
            float4 v = *reinterpret_cast<const float4*>(&Qp[(size_t)r * N_ + n0 + c0 + q4 * 4]);
            qs[r][c0 + q4*4 + 0] = (v.x > 1.0f) ? 2.0f : ALPHA_;
            qs[r][c0 + q4*4 + 1] = (v.y > 1.0f) ? 2.0f : ALPHA_;
            qs[r][c0 + q4*4 + 2] = (v.z > 1.0f) ? 2.0f : ALPHA_;
            qs[r][c0 + q4*4 + 3] = (v.w > 1.0f) ? 2.0f : ALPHA_;
        }
    }
    __syncthreads();

    float q[32];
    #pragma unroll
    for (int d2 = 0; d2 < 32; ++d2) q[d2] = qs[d2][t];

    const float* ksb = ksump + bh * 32;
    float den = 1e-6f;
    #pragma unroll
    for (int d2 = 0; d2 < 32; ++d2) den += q[d2] * ksb[d2];
    float rden = SCALE_ / den;

    const float* kvb = kvp + (size_t)bh * 1024;
    for (int e = 0; e < 32; ++e) {
        float num = 0.0f;
        #pragma unroll
        for (int d2 = 0; d2 < 32; ++d2) num += q[d2] * kvb[d2 * 32 + e];
        att[((size_t)b * C_ + h * HD_ + e) * N_ + n0 + t] = num * rden;
    }
}

// ---------------------------------------------------------------------------
// K5: BatchNorm batch stats per channel (biased var), fp64 accumulation.
// ---------------------------------------------------------------------------
__global__ __launch_bounds__(256) void bn_stats(
    const float* __restrict__ out2, float* __restrict__ stats)
{
    int o = blockIdx.x;
    int t = threadIdx.x;
    double s = 0.0, ss = 0.0;
    for (int b = 0; b < B_; ++b) {
        const float* p = out2 + ((size_t)b * C_ + o) * N_;
        for (int i = t * 4; i < N_; i += 1024) {
            float4 v = *reinterpret_cast<const float4*>(&p[i]);
            s  += (double)v.x + (double)v.y + (double)v.z + (double)v.w;
            ss += (double)v.x * v.x + (double)v.y * v.y + (double)v.z * v.z + (double)v.w * v.w;
        }
    }
    __shared__ double rs[256], rss[256];
    rs[t] = s; rss[t] = ss;
    __syncthreads();
    for (int st = 128; st > 0; st >>= 1) {
        if (t < st) { rs[t] += rs[t + st]; rss[t] += rss[t + st]; }
        __syncthreads();
    }
    if (t == 0) {
        double mean = rs[0] / 32768.0;
        double var  = rss[0] / 32768.0 - mean * mean;
        stats[o * 2 + 0] = (float)mean;
        stats[o * 2 + 1] = (float)(1.0 / sqrt(var + 1e-5));
    }
}

// K6: in-place BN apply
__global__ __launch_bounds__(256) void bn_apply(
    float* __restrict__ out, const float* __restrict__ stats,
    const float* __restrict__ gamma, const float* __restrict__ beta)
{
    size_t i = ((size_t)blockIdx.x * 256 + threadIdx.x) * 4;
    int o = (int)((i >> 12) & 255);
    float m = stats[o * 2], r = stats[o * 2 + 1];
    float g = gamma[o] * r;
    float c = beta[o] - m * g;
    float4 v = *reinterpret_cast<float4*>(&out[i]);
    v.x = v.x * g + c;
    v.y = v.y * g + c;
    v.z = v.z * g + c;
    v.w = v.w * g + c;
    *reinterpret_cast<float4*>(&out[i]) = v;
}

// ---------------------------------------------------------------------------
extern "C" void kernel_launch(void* const* d_in, const int* in_sizes, int n_in,
                              void* d_out, int out_size, void* d_ws, size_t ws_size,
                              hipStream_t stream)
{
    (void)in_sizes; (void)n_in; (void)out_size; (void)ws_size;

    const float* x     = (const float*)d_in[0];
    const float* qmem  = (const float*)d_in[1];
    const float* kmem  = (const float*)d_in[2];
    const float* vmem  = (const float*)d_in[3];
    const float* Wq    = (const float*)d_in[4];
    const float* Wk    = (const float*)d_in[5];
    const float* Wv    = (const float*)d_in[6];
    const float* Wo    = (const float*)d_in[7];
    const float* gamma = (const float*)d_in[8];
    const float* beta  = (const float*)d_in[9];

    const size_t TSZ = (size_t)B_ * C_ * N_;
    float* out0 = (float*)d_out;
    float* outq = out0 + TSZ;
    float* outk = outq + TSZ;
    float* outv = outk + TSZ;

    float* att   = (float*)d_ws;
    float* kvp   = att + TSZ;
    float* ksump = kvp + 64 * 1024;
    float* stats = ksump + 64 * 32;

    dim3 blk(256);

    // K1: fused QKV conv + LIF
    gemm_qkv<<<dim3(32, 2, 8), blk, 0, stream>>>(
        x, Wq, Wk, Wv, qmem, kmem, vmem, outq, outk, outv);

    // K2: kv + ksum per (b,h)
    kv_kernel<<<dim3(64), blk, 0, stream>>>(outk, outv, kvp, ksump);

    // K3: attention -> att
    att_kernel<<<dim3(16, 64), blk, 0, stream>>>(outq, kvp, ksump, att);

    // K4: Wo conv
    gemm_wo<<<dim3(32, 2, 8), blk, 0, stream>>>(att, Wo, out0);

    // K5/K6: BatchNorm
    bn_stats<<<dim3(256), blk, 0, stream>>>(out0, stats);
    bn_apply<<<dim3(8192), blk, 0, stream>>>(out0, stats, gamma, beta);
}

// Round 3
// 206.176 us; speedup vs baseline: 1.9006x; 1.9006x over previous
//
#include <hip/hip_runtime.h>

#define B_ 8
#define C_ 256
#define N_ 4096
#define HD_ 32

#define ALPHA_ 0.36787944117144233f   // elu(-1)+1 = e^-1
#define BETAS_ (2.0f - ALPHA_)        // spike value 2.0 = ALPHA_ + BETAS_
#define SCALE_ 0.17677669529663687f   // 32^-0.5

typedef _Float16 f16;
typedef _Float16 f16x8 __attribute__((ext_vector_type(8)));
typedef float f32x4 __attribute__((ext_vector_type(4)));

__device__ inline f16x8 as_f16x8(uint4 u) { union { uint4 a; f16x8 b; } c; c.a = u; return c.b; }

#define MFMA(a,b,c) __builtin_amdgcn_mfma_f32_16x16x32_f16((a),(b),(c),0,0,0)

// ---------------------------------------------------------------------------
// K0a: transpose + split X: x[b][i][n] f32 -> XTh/XTl[b][n][i] f16
// ---------------------------------------------------------------------------
__global__ __launch_bounds__(256) void transpose_split(
    const float* __restrict__ x, f16* __restrict__ XTh, f16* __restrict__ XTl)
{
    __shared__ float tile[32][257];
    int t = threadIdx.x;
    int b = blockIdx.z, i0 = blockIdx.y * 32, n0 = blockIdx.x * 256;
    const float* src = x + ((size_t)b * C_ + i0) * N_ + n0;
    int r = t >> 3, c0 = (t & 7) * 32;
    #pragma unroll
    for (int q = 0; q < 8; ++q) {
        float4 v = *reinterpret_cast<const float4*>(src + (size_t)r * N_ + c0 + q * 4);
        tile[r][c0 + q*4 + 0] = v.x; tile[r][c0 + q*4 + 1] = v.y;
        tile[r][c0 + q*4 + 2] = v.z; tile[r][c0 + q*4 + 3] = v.w;
    }
    __syncthreads();
    size_t ob = ((size_t)b * N_ + n0 + t) * C_ + i0;
    #pragma unroll
    for (int q = 0; q < 4; ++q) {
        f16x8 hv, lv;
        #pragma unroll
        for (int j = 0; j < 8; ++j) {
            float v = tile[q*8 + j][t];
            f16 h = (f16)v;
            hv[j] = h;
            lv[j] = (f16)(v - (float)h);
        }
        *reinterpret_cast<f16x8*>(XTh + ob + q*8) = hv;
        *reinterpret_cast<f16x8*>(XTl + ob + q*8) = lv;
    }
}

// ---------------------------------------------------------------------------
// K0b: split weights into Wc[1024][256]: rows 0-255 Wq, 256-511 Wk, 512-767 Wv,
// 768-1023 Wo.
// ---------------------------------------------------------------------------
__global__ __launch_bounds__(256) void weight_split(
    const float* __restrict__ Wq, const float* __restrict__ Wk,
    const float* __restrict__ Wv, const float* __restrict__ Wo,
    f16* __restrict__ Wch, f16* __restrict__ Wcl)
{
    int idx4 = (blockIdx.x * 256 + threadIdx.x) * 4;   // 262144 elems
    int o = idx4 >> 8, i = idx4 & 255;
    const float* src = (o < 256) ? (Wq + (size_t)o * 256)
                     : (o < 512) ? (Wk + (size_t)(o - 256) * 256)
                     : (o < 768) ? (Wv + (size_t)(o - 512) * 256)
                                 : (Wo + (size_t)(o - 768) * 256);
    float4 v = *reinterpret_cast<const float4*>(src + i);
    f16 h0 = (f16)v.x, h1 = (f16)v.y, h2 = (f16)v.z, h3 = (f16)v.w;
    f16 hh[4] = { h0, h1, h2, h3 };
    f16 ll[4] = { (f16)(v.x - (float)h0), (f16)(v.y - (float)h1),
                  (f16)(v.z - (float)h2), (f16)(v.w - (float)h3) };
    *reinterpret_cast<uint2*>(Wch + idx4) = *reinterpret_cast<uint2*>(hh);
    *reinterpret_cast<uint2*>(Wcl + idx4) = *reinterpret_cast<uint2*>(ll);
}

// ---------------------------------------------------------------------------
// MFMA GEMM: out[o,n] = sum_i Wc[o,i] * B[n,i], split fp16 (3 MFMA terms).
// Block tile 128o x 256n, 4 waves (2m x 2n), wave tile 64 x 128, K-step 32.
// LDS rows are 128B (8x16B chunks: 0-3 hi, 4-7 lo), chunk-swizzled c^(r&7).
// XCD-grouped block swizzle: same (b, n-tile) group lands on one XCD.
// LIF=1: Y=6 (o 0..767, QKV + LIF epilogue).  LIF=0: Y=2 (o 768..1023, plain).
// ---------------------------------------------------------------------------
template<int Y, bool LIF>
__global__ __launch_bounds__(256) void mfma_gemm(
    const f16* __restrict__ Wch, const f16* __restrict__ Wcl,
    const f16* __restrict__ Bh,  const f16* __restrict__ Bl,
    const float* __restrict__ mq, const float* __restrict__ mk2,
    const float* __restrict__ mv,
    float* __restrict__ o0, float* __restrict__ o1, float* __restrict__ o2)
{
    int gid = blockIdx.x;
    int xcd = gid & 7, slot = gid >> 3;
    int y = slot % Y, gl = slot / Y;
    int grp = xcd * 16 + gl;              // 0..127
    int b = grp >> 4, xt = grp & 15;
    int oBase = (LIF ? 0 : 768) + y * 128;
    int nT = xt * 256;

    const float* memP = nullptr; float* outP; int chBase;
    if (LIF) {
        int conv = y >> 1;
        memP = (conv == 0) ? mq : (conv == 1) ? mk2 : mv;
        outP = (conv == 0) ? o0 : (conv == 1) ? o1 : o2;
        chBase = (y & 1) * 128;
    } else { outP = o0; chBase = y * 128; }

    __shared__ uint4 sm[128 * 8 + 256 * 8];   // 48 KB: A then B
    uint4* sA = sm;
    uint4* sB = sm + 128 * 8;

    int t = threadIdx.x;
    int wid = t >> 6, lane = t & 63;
    int wm = wid >> 1, wn = wid & 1;
    int lr = lane & 15, g = lane >> 4;

    f32x4 acc[4][8];
    #pragma unroll
    for (int m = 0; m < 4; ++m)
        #pragma unroll
        for (int n = 0; n < 8; ++n) acc[m][n] = (f32x4){0.f, 0.f, 0.f, 0.f};

    for (int k0 = 0; k0 < 256; k0 += 32) {
        // stage A (128 rows x 64B per plane): 2 threads/row
        {
            int r = t >> 1, h = t & 1;
            size_t gb = (size_t)(oBase + r) * 256 + k0 + h * 16;
            const uint4* ph = reinterpret_cast<const uint4*>(Wch + gb);
            const uint4* pl = reinterpret_cast<const uint4*>(Wcl + gb);
            uint4 a0 = ph[0], a1 = ph[1], a2 = pl[0], a3 = pl[1];
            int rb = r * 8, s = r & 7;
            sA[rb + ((2*h + 0) ^ s)] = a0;
            sA[rb + ((2*h + 1) ^ s)] = a1;
            sA[rb + ((2*h + 4) ^ s)] = a2;
            sA[rb + ((2*h + 5) ^ s)] = a3;
        }
        // stage B (256 rows x 64B per plane): 1 thread/row
        {
            int r = t;
            size_t gb = ((size_t)b * N_ + nT + r) * 256 + k0;
            const uint4* ph = reinterpret_cast<const uint4*>(Bh + gb);
            const uint4* pl = reinterpret_cast<const uint4*>(Bl + gb);
            uint4 b0 = ph[0], b1 = ph[1], b2 = ph[2], b3 = ph[3];
            uint4 c0 = pl[0], c1 = pl[1], c2 = pl[2], c3 = pl[3];
            int rb = r * 8, s = r & 7;
            sB[rb + (0 ^ s)] = b0; sB[rb + (1 ^ s)] = b1;
            sB[rb + (2 ^ s)] = b2; sB[rb + (3 ^ s)] = b3;
            sB[rb + (4 ^ s)] = c0; sB[rb + (5 ^ s)] = c1;
            sB[rb + (6 ^ s)] = c2; sB[rb + (7 ^ s)] = c3;
        }
        __syncthreads();

        f16x8 ah[4], al[4];
        #pragma unroll
        for (int m = 0; m < 4; ++m) {
            int r = wm * 64 + m * 16 + lr;
            ah[m] = as_f16x8(sA[r * 8 + (g ^ (r & 7))]);
            al[m] = as_f16x8(sA[r * 8 + ((g + 4) ^ (r & 7))]);
        }
        #pragma unroll
        for (int n = 0; n < 8; ++n) {
            int r = wn * 128 + n * 16 + lr;
            f16x8 bh8 = as_f16x8(sB[r * 8 + (g ^ (r & 7))]);
            f16x8 bl8 = as_f16x8(sB[r * 8 + ((g + 4) ^ (r & 7))]);
            #pragma unroll
            for (int m = 0; m < 4; ++m) {
                acc[m][n] = MFMA(ah[m], bh8, acc[m][n]);
                acc[m][n] = MFMA(ah[m], bl8, acc[m][n]);
                acc[m][n] = MFMA(al[m], bh8, acc[m][n]);
            }
        }
        __syncthreads();
    }

    // epilogue: D layout col = lane&15, row = (lane>>4)*4 + reg
    #pragma unroll
    for (int m = 0; m < 4; ++m) {
        int oLoc = chBase + wm * 64 + m * 16 + g * 4;
        #pragma unroll
        for (int n = 0; n < 8; ++n) {
            int nn = nT + wn * 128 + n * 16 + lr;
            #pragma unroll
            for (int r = 0; r < 4; ++r) {
                size_t idx = ((size_t)b * C_ + oLoc + r) * N_ + nn;
                float v = acc[m][n][r];
                if (LIF) {
                    float mm = memP[idx];
                    outP[idx] = 0.5f * mm + v - (mm > 1.0f ? 1.0f : 0.0f);
                } else {
                    outP[idx] = v;
                }
            }
        }
    }
}

// ---------------------------------------------------------------------------
// K2 stage 1: per (bh, n-slice of 512): partial popcounts via 64-bit ballots.
// ---------------------------------------------------------------------------
__global__ __launch_bounds__(256) void kv_stage1(
    const float* __restrict__ Km, const float* __restrict__ Vm,
    int* __restrict__ pkv, int* __restrict__ pck, int* __restrict__ pcv)
{
    int bh = blockIdx.x, sl = blockIdx.y;
    int b = bh >> 3, h = bh & 7;
    const float* Kp = Km + ((size_t)(b * C_ + h * HD_)) * N_ + sl * 512;
    const float* Vp = Vm + ((size_t)(b * C_ + h * HD_)) * N_ + sl * 512;

    __shared__ unsigned long long mk[32][9], mv[32][9];
    int t = threadIdx.x, wave = t >> 6, lane = t & 63;

    for (int r = wave; r < 32; r += 4) {
        const float* kr = Kp + (size_t)r * N_;
        const float* vr = Vp + (size_t)r * N_;
        #pragma unroll
        for (int seg = 0; seg < 2; ++seg) {
            float4 kf = *reinterpret_cast<const float4*>(kr + seg * 256 + lane * 4);
            float4 vf = *reinterpret_cast<const float4*>(vr + seg * 256 + lane * 4);
            unsigned long long k0 = __ballot(kf.x > 1.0f);
            unsigned long long k1 = __ballot(kf.y > 1.0f);
            unsigned long long k2 = __ballot(kf.z > 1.0f);
            unsigned long long k3 = __ballot(kf.w > 1.0f);
            unsigned long long v0 = __ballot(vf.x > 1.0f);
            unsigned long long v1 = __ballot(vf.y > 1.0f);
            unsigned long long v2 = __ballot(vf.z > 1.0f);
            unsigned long long v3 = __ballot(vf.w > 1.0f);
            if (lane == 0) {
                mk[r][seg*4+0] = k0; mk[r][seg*4+1] = k1;
                mk[r][seg*4+2] = k2; mk[r][seg*4+3] = k3;
                mv[r][seg*4+0] = v0; mv[r][seg*4+1] = v1;
                mv[r][seg*4+2] = v2; mv[r][seg*4+3] = v3;
            }
        }
    }
    __syncthreads();

    int base = (bh * 8 + sl);
    int d = t >> 3, e0 = (t & 7) * 4;
    #pragma unroll
    for (int j = 0; j < 4; ++j) {
        int e = e0 + j, P = 0;
        #pragma unroll
        for (int w = 0; w < 8; ++w) P += __popcll(mk[d][w] & mv[e][w]);
        pkv[(size_t)base * 1024 + d * 32 + e] = P;
    }
    if (t < 32) {
        int c = 0;
        #pragma unroll
        for (int w = 0; w < 8; ++w) c += __popcll(mk[t][w]);
        pck[base * 32 + t] = c;
    } else if (t < 64) {
        int dd = t - 32, c = 0;
        #pragma unroll
        for (int w = 0; w < 8; ++w) c += __popcll(mv[dd][w]);
        pcv[base * 32 + dd] = c;
    }
}

// K2 stage 2: reduce 8 slices -> kvp, ksump
__global__ __launch_bounds__(256) void kv_stage2(
    const int* __restrict__ pkv, const int* __restrict__ pck,
    const int* __restrict__ pcv, float* __restrict__ kvp, float* __restrict__ ksump)
{
    int bh = blockIdx.x, t = threadIdx.x;
    __shared__ float ck[32], cv[32];
    if (t < 32) {
        int s = 0;
        #pragma unroll
        for (int sl = 0; sl < 8; ++sl) s += pck[(bh * 8 + sl) * 32 + t];
        ck[t] = (float)s;
    } else if (t < 64) {
        int dd = t - 32, s = 0;
        #pragma unroll
        for (int sl = 0; sl < 8; ++sl) s += pcv[(bh * 8 + sl) * 32 + dd];
        cv[dd] = (float)s;
    }
    __syncthreads();
    int d = t >> 3, e0 = (t & 7) * 4;
    #pragma unroll
    for (int j = 0; j < 4; ++j) {
        int e = e0 + j, P = 0;
        #pragma unroll
        for (int sl = 0; sl < 8; ++sl) P += pkv[(size_t)(bh * 8 + sl) * 1024 + d * 32 + e];
        float skv = 2.0f * (float)P - ck[d];
        float sv  = 2.0f * cv[e] - 4096.0f;
        kvp[(size_t)bh * 1024 + d * 32 + e] = ALPHA_ * sv + BETAS_ * skv;
    }
    if ((t & 7) == 0)
        ksump[bh * 32 + d] = ALPHA_ * 4096.0f + BETAS_ * ck[d];
}

// ---------------------------------------------------------------------------
// K3: att = SCALE*(q.kv)/(q.ksum+1e-6), output split fp16 ATh/ATl [b][n][c]
// ---------------------------------------------------------------------------
__global__ __launch_bounds__(256) void att_kernel(
    const float* __restrict__ Qm, const float* __restrict__ kvp,
    const float* __restrict__ ksump, f16* __restrict__ ATh, f16* __restrict__ ATl)
{
    int bh = blockIdx.y; int b = bh >> 3, h = bh & 7;
    int n0 = blockIdx.x * 256;
    const float* Qp = Qm + ((size_t)(b * C_ + h * HD_)) * N_;

    __shared__ float qs[32][260];
    int t = threadIdx.x;
    {
        int r  = t >> 3, c0 = (t & 7) * 32;
        #pragma unroll
        for (int q4 = 0; q4 < 8; ++q4) {
            float4 v = *reinterpret_cast<const float4*>(&Qp[(size_t)r * N_ + n0 + c0 + q4 * 4]);
            qs[r][c0 + q4*4 + 0] = (v.x > 1.0f) ? 2.0f : ALPHA_;
            qs[r][c0 + q4*4 + 1] = (v.y > 1.0f) ? 2.0f : ALPHA_;
            qs[r][c0 + q4*4 + 2] = (v.z > 1.0f) ? 2.0f : ALPHA_;
            qs[r][c0 + q4*4 + 3] = (v.w > 1.0f) ? 2.0f : ALPHA_;
        }
    }
    __syncthreads();

    float q[32];
    #pragma unroll
    for (int d2 = 0; d2 < 32; ++d2) q[d2] = qs[d2][t];

    const float* ksb = ksump + bh * 32;
    float den = 1e-6f;
    #pragma unroll
    for (int d2 = 0; d2 < 32; ++d2) den += q[d2] * ksb[d2];
    float rden = SCALE_ / den;

    const float* kvb = kvp + (size_t)bh * 1024;
    size_t ob = ((size_t)b * N_ + n0 + t) * C_ + h * HD_;
    #pragma unroll
    for (int qq = 0; qq < 4; ++qq) {
        f16x8 hv, lv;
        #pragma unroll
        for (int j = 0; j < 8; ++j) {
            int e = qq * 8 + j;
            float num = 0.0f;
            #pragma unroll
            for (int d2 = 0; d2 < 32; ++d2) num += q[d2] * kvb[d2 * 32 + e];
            float val = num * rden;
            f16 hh = (f16)val;
            hv[j] = hh;
            lv[j] = (f16)(val - (float)hh);
        }
        *reinterpret_cast<f16x8*>(ATh + ob + qq * 8) = hv;
        *reinterpret_cast<f16x8*>(ATl + ob + qq * 8) = lv;
    }
}

// ---------------------------------------------------------------------------
// K5: BN batch stats per channel (biased var), fp64 accumulation.
// ---------------------------------------------------------------------------
__global__ __launch_bounds__(1024) void bn_stats(
    const float* __restrict__ out2, float* __restrict__ stats)
{
    int o = blockIdx.x, t = threadIdx.x;
    double s = 0.0, ss = 0.0;
    for (int b = 0; b < B_; ++b) {
        const float* p = out2 + ((size_t)b * C_ + o) * N_;
        float4 v = *reinterpret_cast<const float4*>(&p[t * 4]);
        s  += (double)v.x + (double)v.y + (double)v.z + (double)v.w;
        ss += (double)v.x * v.x + (double)v.y * v.y + (double)v.z * v.z + (double)v.w * v.w;
    }
    __shared__ double rs[1024], rss[1024];
    rs[t] = s; rss[t] = ss;
    __syncthreads();
    for (int st = 512; st > 0; st >>= 1) {
        if (t < st) { rs[t] += rs[t + st]; rss[t] += rss[t + st]; }
        __syncthreads();
    }
    if (t == 0) {
        double mean = rs[0] / 32768.0;
        double var  = rss[0] / 32768.0 - mean * mean;
        stats[o * 2 + 0] = (float)mean;
        stats[o * 2 + 1] = (float)(1.0 / sqrt(var + 1e-5));
    }
}

// K6: in-place BN apply
__global__ __launch_bounds__(256) void bn_apply(
    float* __restrict__ out, const float* __restrict__ stats,
    const float* __restrict__ gamma, const float* __restrict__ beta)
{
    size_t i = ((size_t)blockIdx.x * 256 + threadIdx.x) * 4;
    int o = (int)((i >> 12) & 255);
    float m = stats[o * 2], r = stats[o * 2 + 1];
    float g = gamma[o] * r;
    float c = beta[o] - m * g;
    float4 v = *reinterpret_cast<float4*>(&out[i]);
    v.x = v.x * g + c; v.y = v.y * g + c;
    v.z = v.z * g + c; v.w = v.w * g + c;
    *reinterpret_cast<float4*>(&out[i]) = v;
}

// ---------------------------------------------------------------------------
extern "C" void kernel_launch(void* const* d_in, const int* in_sizes, int n_in,
                              void* d_out, int out_size, void* d_ws, size_t ws_size,
                              hipStream_t stream)
{
    (void)in_sizes; (void)n_in; (void)out_size; (void)ws_size;

    const float* x     = (const float*)d_in[0];
    const float* qmem  = (const float*)d_in[1];
    const float* kmem  = (const float*)d_in[2];
    const float* vmem  = (const float*)d_in[3];
    const float* Wq    = (const float*)d_in[4];
    const float* Wk    = (const float*)d_in[5];
    const float* Wv    = (const float*)d_in[6];
    const float* Wo    = (const float*)d_in[7];
    const float* gamma = (const float*)d_in[8];
    const float* beta  = (const float*)d_in[9];

    const size_t TSZ = (size_t)B_ * C_ * N_;     // 8,388,608
    float* out0 = (float*)d_out;
    float* outq = out0 + TSZ;
    float* outk = outq + TSZ;
    float* outv = outk + TSZ;

    char* w = (char*)d_ws;
    f16* XTh = (f16*)w;           w += TSZ * 2;
    f16* XTl = (f16*)w;           w += TSZ * 2;
    f16* ATh = (f16*)w;           w += TSZ * 2;
    f16* ATl = (f16*)w;           w += TSZ * 2;
    f16* Wch = (f16*)w;           w += 1024 * 256 * 2;
    f16* Wcl = (f16*)w;           w += 1024 * 256 * 2;
    int* pkv = (int*)w;           w += 64 * 8 * 1024 * 4;
    int* pck = (int*)w;           w += 64 * 8 * 32 * 4;
    int* pcv = (int*)w;           w += 64 * 8 * 32 * 4;
    float* kvp   = (float*)w;     w += 64 * 1024 * 4;
    float* ksump = (float*)w;     w += 64 * 32 * 4;
    float* stats = (float*)w;     w += 256 * 2 * 4;

    dim3 blk(256);

    // K0: transpose/split X, split weights
    transpose_split<<<dim3(16, 8, 8), blk, 0, stream>>>(x, XTh, XTl);
    weight_split<<<dim3(256), blk, 0, stream>>>(Wq, Wk, Wv, Wo, Wch, Wcl);

    // K1: QKV GEMM (MFMA split-fp16) + LIF
    mfma_gemm<6, true><<<dim3(768), blk, 0, stream>>>(
        Wch, Wcl, XTh, XTl, qmem, kmem, vmem, outq, outk, outv);

    // K2: exact kv/ksum via two-stage popcount
    kv_stage1<<<dim3(64, 8), blk, 0, stream>>>(outk, outv, pkv, pck, pcv);
    kv_stage2<<<dim3(64), blk, 0, stream>>>(pkv, pck, pcv, kvp, ksump);

    // K3: attention -> split fp16 ATh/ATl [b][n][c]
    att_kernel<<<dim3(16, 64), blk, 0, stream>>>(outq, kvp, ksump, ATh, ATl);

    // K4: Wo GEMM (MFMA split-fp16) -> out0
    mfma_gemm<2, false><<<dim3(256), blk, 0, stream>>>(
        Wch, Wcl, ATh, ATl, nullptr, nullptr, nullptr, out0, nullptr, nullptr);

    // K5/K6: BatchNorm
    bn_stats<<<dim3(256), dim3(1024), 0, stream>>>(out0, stats);
    bn_apply<<<dim3(8192), blk, 0, stream>>>(out0, stats, gamma, beta);
}

// Round 4
// 184.593 us; speedup vs baseline: 2.1228x; 1.1169x over previous
//
#include <hip/hip_runtime.h>

#define B_ 8
#define C_ 256
#define N_ 4096
#define HD_ 32

#define ALPHA_ 0.36787944117144233f   // elu(-1)+1 = e^-1
#define BETAS_ (2.0f - ALPHA_)        // spike value 2.0 = ALPHA_ + BETAS_
#define SCALE_ 0.17677669529663687f   // 32^-0.5

typedef _Float16 f16;
typedef _Float16 f16x8 __attribute__((ext_vector_type(8)));
typedef float f32x4 __attribute__((ext_vector_type(4)));

#define MFMA(a,b,c) __builtin_amdgcn_mfma_f32_16x16x32_f16((a),(b),(c),0,0,0)

#define GLDS(g, l) __builtin_amdgcn_global_load_lds( \
    (const __attribute__((address_space(1))) void*)(g), \
    (__attribute__((address_space(3))) void*)(l), 16, 0, 0)

// ---------------------------------------------------------------------------
// K0a: transpose + split X: x[b][i][n] f32 -> XTh/XTl[b][n][i] f16
// ---------------------------------------------------------------------------
__global__ __launch_bounds__(256) void transpose_split(
    const float* __restrict__ x, f16* __restrict__ XTh, f16* __restrict__ XTl)
{
    __shared__ float tile[32][257];
    int t = threadIdx.x;
    int b = blockIdx.z, i0 = blockIdx.y * 32, n0 = blockIdx.x * 256;
    const float* src = x + ((size_t)b * C_ + i0) * N_ + n0;
    int r = t >> 3, c0 = (t & 7) * 32;
    #pragma unroll
    for (int q = 0; q < 8; ++q) {
        float4 v = *reinterpret_cast<const float4*>(src + (size_t)r * N_ + c0 + q * 4);
        tile[r][c0 + q*4 + 0] = v.x; tile[r][c0 + q*4 + 1] = v.y;
        tile[r][c0 + q*4 + 2] = v.z; tile[r][c0 + q*4 + 3] = v.w;
    }
    __syncthreads();
    size_t ob = ((size_t)b * N_ + n0 + t) * C_ + i0;
    #pragma unroll
    for (int q = 0; q < 4; ++q) {
        f16x8 hv, lv;
        #pragma unroll
        for (int j = 0; j < 8; ++j) {
            float v = tile[q*8 + j][t];
            f16 h = (f16)v;
            hv[j] = h;
            lv[j] = (f16)(v - (float)h);
        }
        *reinterpret_cast<f16x8*>(XTh + ob + q*8) = hv;
        *reinterpret_cast<f16x8*>(XTl + ob + q*8) = lv;
    }
}

// ---------------------------------------------------------------------------
// K0b: split weights into Wc[1024][256]: rows 0-255 Wq, 256-511 Wk, 512-767 Wv,
// 768-1023 Wo.
// ---------------------------------------------------------------------------
__global__ __launch_bounds__(256) void weight_split(
    const float* __restrict__ Wq, const float* __restrict__ Wk,
    const float* __restrict__ Wv, const float* __restrict__ Wo,
    f16* __restrict__ Wch, f16* __restrict__ Wcl)
{
    int idx4 = (blockIdx.x * 256 + threadIdx.x) * 4;   // 262144 elems
    int o = idx4 >> 8, i = idx4 & 255;
    const float* src = (o < 256) ? (Wq + (size_t)o * 256)
                     : (o < 512) ? (Wk + (size_t)(o - 256) * 256)
                     : (o < 768) ? (Wv + (size_t)(o - 512) * 256)
                                 : (Wo + (size_t)(o - 768) * 256);
    float4 v = *reinterpret_cast<const float4*>(src + i);
    f16 h0 = (f16)v.x, h1 = (f16)v.y, h2 = (f16)v.z, h3 = (f16)v.w;
    f16 hh[4] = { h0, h1, h2, h3 };
    f16 ll[4] = { (f16)(v.x - (float)h0), (f16)(v.y - (float)h1),
                  (f16)(v.z - (float)h2), (f16)(v.w - (float)h3) };
    *reinterpret_cast<uint2*>(Wch + idx4) = *reinterpret_cast<uint2*>(hh);
    *reinterpret_cast<uint2*>(Wcl + idx4) = *reinterpret_cast<uint2*>(ll);
}

// ---------------------------------------------------------------------------
// MFMA GEMM, m97 structure: out[o,n] = sum_i Wc[o,i]*B[n,i], split fp16.
// Block tile 128o x 256n, K-step 32, 4 waves (2m x 2n), wave tile 64x128.
// Staging via global_load_lds(16B): LDS lane-linear, global source chunk
// index XOR-permuted (c ^ ((r>>1)&3)); fragment ds_read applies the same
// involution -> <=2-way bank aliasing (free), full 64B global lines.
// LDS slots (16B): A_h [0,512) [r*4+c], A_l [512,1024),
//                  B_h [1024,2048) [r*4+c], B_l [2048,3072).  48 KB total.
// ---------------------------------------------------------------------------
template<int Y, bool LIF>
__global__ __launch_bounds__(256, 2) void mfma_gemm(
    const f16* __restrict__ Wch, const f16* __restrict__ Wcl,
    const f16* __restrict__ Bh,  const f16* __restrict__ Bl,
    const float* __restrict__ mq, const float* __restrict__ mk2,
    const float* __restrict__ mv,
    float* __restrict__ o0, float* __restrict__ o1, float* __restrict__ o2)
{
    int gid = blockIdx.x;
    int xcd = gid & 7, slot = gid >> 3;
    int y = slot % Y, gl = slot / Y;
    int b = xcd, xt = gl;                       // per-XCD: one batch's XT in L2
    int oBase = (LIF ? 0 : 768) + y * 128;
    int nT = xt * 256;

    const float* memP = nullptr; float* outP; int chBase;
    if (LIF) {
        int conv = y >> 1;
        memP = (conv == 0) ? mq : (conv == 1) ? mk2 : mv;
        outP = (conv == 0) ? o0 : (conv == 1) ? o1 : o2;
        chBase = (y & 1) * 128;
    } else { outP = o0; chBase = y * 128; }

    __shared__ f16 sm[3072 * 8];                // 48 KB

    int t = threadIdx.x;
    int wid = t >> 6, lane = t & 63;
    int wm = wid >> 1, wn = wid & 1;
    int lr = lane & 15, g = lane >> 4;

    // per-thread global source base pointers (k0 = 0), statically indexed
    const f16* g0[12];
    #pragma unroll
    for (int i = 0; i < 12; ++i) {
        int s = wid * 768 + i * 64 + lane;
        const f16* gp;
        if (s < 512) {
            int r = s >> 2, c = (s & 3) ^ ((r >> 1) & 3);
            gp = Wch + (size_t)(oBase + r) * 256 + c * 8;
        } else if (s < 1024) {
            int s2 = s - 512; int r = s2 >> 2, c = (s2 & 3) ^ ((r >> 1) & 3);
            gp = Wcl + (size_t)(oBase + r) * 256 + c * 8;
        } else if (s < 2048) {
            int s2 = s - 1024; int r = s2 >> 2, c = (s2 & 3) ^ ((r >> 1) & 3);
            gp = Bh + ((size_t)b * N_ + nT + r) * 256 + c * 8;
        } else {
            int s2 = s - 2048; int r = s2 >> 2, c = (s2 & 3) ^ ((r >> 1) & 3);
            gp = Bl + ((size_t)b * N_ + nT + r) * 256 + c * 8;
        }
        g0[i] = gp;
    }

    f32x4 acc[4][8];
    #pragma unroll
    for (int m = 0; m < 4; ++m)
        #pragma unroll
        for (int n = 0; n < 8; ++n) acc[m][n] = (f32x4){0.f, 0.f, 0.f, 0.f};

    for (int k0 = 0; k0 < 256; k0 += 32) {
        #pragma unroll
        for (int i = 0; i < 12; ++i) {
            int s = wid * 768 + i * 64 + lane;
            GLDS(g0[i] + k0, &sm[s * 8]);
        }
        __syncthreads();                        // drains vmcnt(0)

        f16x8 ah[4], al[4];
        #pragma unroll
        for (int m = 0; m < 4; ++m) {
            int r = wm * 64 + m * 16 + lr;
            int sw = g ^ ((r >> 1) & 3);
            ah[m] = *reinterpret_cast<const f16x8*>(&sm[(r * 4 + sw) * 8]);
            al[m] = *reinterpret_cast<const f16x8*>(&sm[(512 + r * 4 + sw) * 8]);
        }
        #pragma unroll
        for (int n = 0; n < 8; ++n) {
            int r = wn * 128 + n * 16 + lr;
            int sw = g ^ ((r >> 1) & 3);
            f16x8 bh8 = *reinterpret_cast<const f16x8*>(&sm[(1024 + r * 4 + sw) * 8]);
            f16x8 bl8 = *reinterpret_cast<const f16x8*>(&sm[(2048 + r * 4 + sw) * 8]);
            #pragma unroll
            for (int m = 0; m < 4; ++m) {
                acc[m][n] = MFMA(ah[m], bh8, acc[m][n]);
                acc[m][n] = MFMA(ah[m], bl8, acc[m][n]);
                acc[m][n] = MFMA(al[m], bh8, acc[m][n]);
            }
        }
        __syncthreads();
    }

    // epilogue: D layout col = lane&15, row = (lane>>4)*4 + reg
    #pragma unroll
    for (int m = 0; m < 4; ++m) {
        int oLoc = chBase + wm * 64 + m * 16 + g * 4;
        #pragma unroll
        for (int n = 0; n < 8; ++n) {
            int nn = nT + wn * 128 + n * 16 + lr;
            #pragma unroll
            for (int r = 0; r < 4; ++r) {
                size_t idx = ((size_t)b * C_ + oLoc + r) * N_ + nn;
                float v = acc[m][n][r];
                if (LIF) {
                    float mm = memP[idx];
                    outP[idx] = 0.5f * mm + v - (mm > 1.0f ? 1.0f : 0.0f);
                } else {
                    outP[idx] = v;
                }
            }
        }
    }
}

// ---------------------------------------------------------------------------
// K2 stage 1: per (bh, n-slice of 512): partial popcounts via 64-bit ballots.
// ---------------------------------------------------------------------------
__global__ __launch_bounds__(256) void kv_stage1(
    const float* __restrict__ Km, const float* __restrict__ Vm,
    int* __restrict__ pkv, int* __restrict__ pck, int* __restrict__ pcv)
{
    int bh = blockIdx.x, sl = blockIdx.y;
    int b = bh >> 3, h = bh & 7;
    const float* Kp = Km + ((size_t)(b * C_ + h * HD_)) * N_ + sl * 512;
    const float* Vp = Vm + ((size_t)(b * C_ + h * HD_)) * N_ + sl * 512;

    __shared__ unsigned long long mk[32][9], mv[32][9];
    int t = threadIdx.x, wave = t >> 6, lane = t & 63;

    for (int r = wave; r < 32; r += 4) {
        const float* kr = Kp + (size_t)r * N_;
        const float* vr = Vp + (size_t)r * N_;
        #pragma unroll
        for (int seg = 0; seg < 2; ++seg) {
            float4 kf = *reinterpret_cast<const float4*>(kr + seg * 256 + lane * 4);
            float4 vf = *reinterpret_cast<const float4*>(vr + seg * 256 + lane * 4);
            unsigned long long k0 = __ballot(kf.x > 1.0f);
            unsigned long long k1 = __ballot(kf.y > 1.0f);
            unsigned long long k2 = __ballot(kf.z > 1.0f);
            unsigned long long k3 = __ballot(kf.w > 1.0f);
            unsigned long long v0 = __ballot(vf.x > 1.0f);
            unsigned long long v1 = __ballot(vf.y > 1.0f);
            unsigned long long v2 = __ballot(vf.z > 1.0f);
            unsigned long long v3 = __ballot(vf.w > 1.0f);
            if (lane == 0) {
                mk[r][seg*4+0] = k0; mk[r][seg*4+1] = k1;
                mk[r][seg*4+2] = k2; mk[r][seg*4+3] = k3;
                mv[r][seg*4+0] = v0; mv[r][seg*4+1] = v1;
                mv[r][seg*4+2] = v2; mv[r][seg*4+3] = v3;
            }
        }
    }
    __syncthreads();

    int base = (bh * 8 + sl);
    int d = t >> 3, e0 = (t & 7) * 4;
    #pragma unroll
    for (int j = 0; j < 4; ++j) {
        int e = e0 + j, P = 0;
        #pragma unroll
        for (int w = 0; w < 8; ++w) P += __popcll(mk[d][w] & mv[e][w]);
        pkv[(size_t)base * 1024 + d * 32 + e] = P;
    }
    if (t < 32) {
        int c = 0;
        #pragma unroll
        for (int w = 0; w < 8; ++w) c += __popcll(mk[t][w]);
        pck[base * 32 + t] = c;
    } else if (t < 64) {
        int dd = t - 32, c = 0;
        #pragma unroll
        for (int w = 0; w < 8; ++w) c += __popcll(mv[dd][w]);
        pcv[base * 32 + dd] = c;
    }
}

// K2 stage 2: reduce 8 slices -> kvp, ksump
__global__ __launch_bounds__(256) void kv_stage2(
    const int* __restrict__ pkv, const int* __restrict__ pck,
    const int* __restrict__ pcv, float* __restrict__ kvp, float* __restrict__ ksump)
{
    int bh = blockIdx.x, t = threadIdx.x;
    __shared__ float ck[32], cv[32];
    if (t < 32) {
        int s = 0;
        #pragma unroll
        for (int sl = 0; sl < 8; ++sl) s += pck[(bh * 8 + sl) * 32 + t];
        ck[t] = (float)s;
    } else if (t < 64) {
        int dd = t - 32, s = 0;
        #pragma unroll
        for (int sl = 0; sl < 8; ++sl) s += pcv[(bh * 8 + sl) * 32 + dd];
        cv[dd] = (float)s;
    }
    __syncthreads();
    int d = t >> 3, e0 = (t & 7) * 4;
    #pragma unroll
    for (int j = 0; j < 4; ++j) {
        int e = e0 + j, P = 0;
        #pragma unroll
        for (int sl = 0; sl < 8; ++sl) P += pkv[(size_t)(bh * 8 + sl) * 1024 + d * 32 + e];
        float skv = 2.0f * (float)P - ck[d];
        float sv  = 2.0f * cv[e] - 4096.0f;
        kvp[(size_t)bh * 1024 + d * 32 + e] = ALPHA_ * sv + BETAS_ * skv;
    }
    if ((t & 7) == 0)
        ksump[bh * 32 + d] = ALPHA_ * 4096.0f + BETAS_ * ck[d];
}

// ---------------------------------------------------------------------------
// K3: att = SCALE*(q.kv)/(q.ksum+1e-6), output split fp16 ATh/ATl [b][n][c]
// ---------------------------------------------------------------------------
__global__ __launch_bounds__(256) void att_kernel(
    const float* __restrict__ Qm, const float* __restrict__ kvp,
    const float* __restrict__ ksump, f16* __restrict__ ATh, f16* __restrict__ ATl)
{
    int bh = blockIdx.y; int b = bh >> 3, h = bh & 7;
    int n0 = blockIdx.x * 256;
    const float* Qp = Qm + ((size_t)(b * C_ + h * HD_)) * N_;

    __shared__ float qs[32][260];
    int t = threadIdx.x;
    {
        int r  = t >> 3, c0 = (t & 7) * 32;
        #pragma unroll
        for (int q4 = 0; q4 < 8; ++q4) {
            float4 v = *reinterpret_cast<const float4*>(&Qp[(size_t)r * N_ + n0 + c0 + q4 * 4]);
            qs[r][c0 + q4*4 + 0] = (v.x > 1.0f) ? 2.0f : ALPHA_;
            qs[r][c0 + q4*4 + 1] = (v.y > 1.0f) ? 2.0f : ALPHA_;
            qs[r][c0 + q4*4 + 2] = (v.z > 1.0f) ? 2.0f : ALPHA_;
            qs[r][c0 + q4*4 + 3] = (v.w > 1.0f) ? 2.0f : ALPHA_;
        }
    }
    __syncthreads();

    float q[32];
    #pragma unroll
    for (int d2 = 0; d2 < 32; ++d2) q[d2] = qs[d2][t];

    const float* ksb = ksump + bh * 32;
    float den = 1e-6f;
    #pragma unroll
    for (int d2 = 0; d2 < 32; ++d2) den += q[d2] * ksb[d2];
    float rden = SCALE_ / den;

    const float* kvb = kvp + (size_t)bh * 1024;
    size_t ob = ((size_t)b * N_ + n0 + t) * C_ + h * HD_;
    #pragma unroll
    for (int qq = 0; qq < 4; ++qq) {
        f16x8 hv, lv;
        #pragma unroll
        for (int j = 0; j < 8; ++j) {
            int e = qq * 8 + j;
            float num = 0.0f;
            #pragma unroll
            for (int d2 = 0; d2 < 32; ++d2) num += q[d2] * kvb[d2 * 32 + e];
            float val = num * rden;
            f16 hh = (f16)val;
            hv[j] = hh;
            lv[j] = (f16)(val - (float)hh);
        }
        *reinterpret_cast<f16x8*>(ATh + ob + qq * 8) = hv;
        *reinterpret_cast<f16x8*>(ATl + ob + qq * 8) = lv;
    }
}

// ---------------------------------------------------------------------------
// K5: BN batch stats per channel (biased var), fp64 accumulation.
// ---------------------------------------------------------------------------
__global__ __launch_bounds__(1024) void bn_stats(
    const float* __restrict__ out2, float* __restrict__ stats)
{
    int o = blockIdx.x, t = threadIdx.x;
    double s = 0.0, ss = 0.0;
    for (int b = 0; b < B_; ++b) {
        const float* p = out2 + ((size_t)b * C_ + o) * N_;
        float4 v = *reinterpret_cast<const float4*>(&p[t * 4]);
        s  += (double)v.x + (double)v.y + (double)v.z + (double)v.w;
        ss += (double)v.x * v.x + (double)v.y * v.y + (double)v.z * v.z + (double)v.w * v.w;
    }
    __shared__ double rs[1024], rss[1024];
    rs[t] = s; rss[t] = ss;
    __syncthreads();
    for (int st = 512; st > 0; st >>= 1) {
        if (t < st) { rs[t] += rs[t + st]; rss[t] += rss[t + st]; }
        __syncthreads();
    }
    if (t == 0) {
        double mean = rs[0] / 32768.0;
        double var  = rss[0] / 32768.0 - mean * mean;
        stats[o * 2 + 0] = (float)mean;
        stats[o * 2 + 1] = (float)(1.0 / sqrt(var + 1e-5));
    }
}

// K6: in-place BN apply
__global__ __launch_bounds__(256) void bn_apply(
    float* __restrict__ out, const float* __restrict__ stats,
    const float* __restrict__ gamma, const float* __restrict__ beta)
{
    size_t i = ((size_t)blockIdx.x * 256 + threadIdx.x) * 4;
    int o = (int)((i >> 12) & 255);
    float m = stats[o * 2], r = stats[o * 2 + 1];
    float g = gamma[o] * r;
    float c = beta[o] - m * g;
    float4 v = *reinterpret_cast<float4*>(&out[i]);
    v.x = v.x * g + c; v.y = v.y * g + c;
    v.z = v.z * g + c; v.w = v.w * g + c;
    *reinterpret_cast<float4*>(&out[i]) = v;
}

// ---------------------------------------------------------------------------
extern "C" void kernel_launch(void* const* d_in, const int* in_sizes, int n_in,
                              void* d_out, int out_size, void* d_ws, size_t ws_size,
                              hipStream_t stream)
{
    (void)in_sizes; (void)n_in; (void)out_size; (void)ws_size;

    const float* x     = (const float*)d_in[0];
    const float* qmem  = (const float*)d_in[1];
    const float* kmem  = (const float*)d_in[2];
    const float* vmem  = (const float*)d_in[3];
    const float* Wq    = (const float*)d_in[4];
    const float* Wk    = (const float*)d_in[5];
    const float* Wv    = (const float*)d_in[6];
    const float* Wo    = (const float*)d_in[7];
    const float* gamma = (const float*)d_in[8];
    const float* beta  = (const float*)d_in[9];

    const size_t TSZ = (size_t)B_ * C_ * N_;     // 8,388,608
    float* out0 = (float*)d_out;
    float* outq = out0 + TSZ;
    float* outk = outq + TSZ;
    float* outv = outk + TSZ;

    char* w = (char*)d_ws;
    f16* XTh = (f16*)w;           w += TSZ * 2;
    f16* XTl = (f16*)w;           w += TSZ * 2;
    f16* ATh = (f16*)w;           w += TSZ * 2;
    f16* ATl = (f16*)w;           w += TSZ * 2;
    f16* Wch = (f16*)w;           w += 1024 * 256 * 2;
    f16* Wcl = (f16*)w;           w += 1024 * 256 * 2;
    int* pkv = (int*)w;           w += 64 * 8 * 1024 * 4;
    int* pck = (int*)w;           w += 64 * 8 * 32 * 4;
    int* pcv = (int*)w;           w += 64 * 8 * 32 * 4;
    float* kvp   = (float*)w;     w += 64 * 1024 * 4;
    float* ksump = (float*)w;     w += 64 * 32 * 4;
    float* stats = (float*)w;     w += 256 * 2 * 4;

    dim3 blk(256);

    // K0: transpose/split X, split weights
    transpose_split<<<dim3(16, 8, 8), blk, 0, stream>>>(x, XTh, XTl);
    weight_split<<<dim3(256), blk, 0, stream>>>(Wq, Wk, Wv, Wo, Wch, Wcl);

    // K1: QKV GEMM (MFMA split-fp16, gload_lds staging) + LIF
    mfma_gemm<6, true><<<dim3(768), blk, 0, stream>>>(
        Wch, Wcl, XTh, XTl, qmem, kmem, vmem, outq, outk, outv);

    // K2: exact kv/ksum via two-stage popcount
    kv_stage1<<<dim3(64, 8), blk, 0, stream>>>(outk, outv, pkv, pck, pcv);
    kv_stage2<<<dim3(64), blk, 0, stream>>>(pkv, pck, pcv, kvp, ksump);

    // K3: attention -> split fp16 ATh/ATl [b][n][c]
    att_kernel<<<dim3(16, 64), blk, 0, stream>>>(outq, kvp, ksump, ATh, ATl);

    // K4: Wo GEMM -> out0
    mfma_gemm<2, false><<<dim3(256), blk, 0, stream>>>(
        Wch, Wcl, ATh, ATl, nullptr, nullptr, nullptr, out0, nullptr, nullptr);

    // K5/K6: BatchNorm
    bn_stats<<<dim3(256), dim3(1024), 0, stream>>>(out0, stats);
    bn_apply<<<dim3(8192), blk, 0, stream>>>(out0, stats, gamma, beta);
}